// Round 8
// baseline (341.694 us; speedup 1.0000x reference)
//
#include <hip/hip_runtime.h>

// ---------------------------------------------------------------------------
// sxsGCN: h=[B=128,N=4096,3]; 3x { relu((adj@h)@W+b) }; then FC 12288->54->4096
// bf16 MFMA GEMMs adj[4096x4096] @ H[4096 x 512], H transposed [b*4+f][m].
// R1: fc1 split-K + atomics: 275us -> ~15us.
// R2: gemm double-buffered BK=64: 62 -> 47us.
// R3: XOR-swizzled LDS (conflicts 4.2e6 -> 0): feed/latency-bound, not LDS.
// R4: 128x128+split-K atomics: 1 block/CU -> 53us FAIL.
// R5: deeper split-K: atomic epilogues, short k-chunks: 61.5us FAIL.
// R6: W1 folded into prep, W2*W3 chained in stage-2 epilogue, epilogues fused
//     into gemm, 9 -> 6 dispatches: 296 -> 234us. Profile shows harness 0xAA
//     ws-fill (~41us @ 83% HBM) inside timed window = immovable floor.
// R7: gcn was LDS-read-BW bound (1 ds_read_b128 : 1 MFMA, 64 b128/CU-iter
//     vs ~78 cyc MFMA). B operand now read global->VGPR per-wave (register
//     ping-pong, prefetched one iter ahead, L2-resident); LDS holds A only:
//     LDS reads halve, staging copies halve (shorter vmcnt drain). B L2
//     traffic 2x but total 24KB/block-iter < L2 feed ceiling.
// ---------------------------------------------------------------------------

typedef __bf16 bf16x8 __attribute__((ext_vector_type(8)));
typedef float  f32x4  __attribute__((ext_vector_type(4)));

#define N_NODE 4096
#define BATCH  128

__device__ __forceinline__ void async_copy16(const void* gsrc, void* ldst) {
    __builtin_amdgcn_global_load_lds(
        (const __attribute__((address_space(1))) void*)gsrc,
        (__attribute__((address_space(3))) void*)ldst,
        16, 0, 0);
}

// prep: [0,8192) cast adj->bf16 | [8192,10240) G0[b*4+f][m] = (X@W1)^T bf16
//       | [10240,10267) zero hid
__global__ __launch_bounds__(256) void prep_k(const float* __restrict__ adj,
                                              __bf16* __restrict__ adjB,
                                              const float* __restrict__ X,
                                              const float* __restrict__ W1,
                                              __bf16* __restrict__ G0,
                                              float* __restrict__ hid_acc) {
    const int blk = blockIdx.x, tx = threadIdx.x;
    if (blk < 8192) {
        const size_t i = (size_t)blk * 256 + tx;       // group of 8
        const float4* a4 = (const float4*)adj;
        float4 u = a4[i * 2];
        float4 v = a4[i * 2 + 1];
        bf16x8 o = { (__bf16)u.x, (__bf16)u.y, (__bf16)u.z, (__bf16)u.w,
                     (__bf16)v.x, (__bf16)v.y, (__bf16)v.z, (__bf16)v.w };
        *(bf16x8*)(adjB + i * 8) = o;
    } else if (blk < 10240) {
        const int base = (blk - 8192) * 1024;          // c uniform per block
        const int c = base >> 12, b = c >> 2, f = c & 3;
        const float w0 = W1[0 * 4 + f], w1 = W1[1 * 4 + f], w2 = W1[2 * 4 + f];
        const float* Xb = X + (size_t)b * 12288;
#pragma unroll
        for (int k = 0; k < 4; ++k) {
            const int idx = base + k * 256 + tx;       // < 512*4096
            const int m = idx & 4095;
            const float v = Xb[m * 3 + 0] * w0 + Xb[m * 3 + 1] * w1 + Xb[m * 3 + 2] * w2;
            G0[idx] = (__bf16)v;
        }
    } else {
        const int i = (blk - 10240) * 256 + tx;
        if (i < BATCH * 54) hid_acc[i] = 0.f;
    }
}

// Fused GEMM + epilogue. C[m][c] = sum_k adjB[m][k] * Ht[c][k], tile 64x64,
// 4 waves of 32x32, BK=64. A double-buffered in LDS (XOR-swizzled); B read
// per-wave global->VGPR with register ping-pong one iter ahead.
// Epilogue (LDS transpose, stride 65):
//   MODE 0: h1 = relu(C + b1[f])                       -> Hout bf16
//   MODE 1: g2 = relu(C@W2 + b2) @ W3, f=3 col zeroed  -> Hout bf16
//   MODE 2: h3 = relu(C + b3[f]), f<3                  -> H3out fp32
// XCD swizzle: l&7 = xcd; mi = xcd*8 + (s&7), ci = s>>3.
template <int MODE>
__global__ __launch_bounds__(256) void gcn_k(const __bf16* __restrict__ A,
                                             const __bf16* __restrict__ Bt,
                                             const float* __restrict__ Wa,
                                             const float* __restrict__ ba,
                                             const float* __restrict__ Wb,
                                             __bf16* __restrict__ Hout,
                                             float* __restrict__ H3out) {
    __shared__ __align__(16) __bf16 As[2][2][2048];   // [buf][kh][64r][32k] swizzled
    __shared__ __align__(16) float  Ct[64 * 65];
    const int tx   = threadIdx.x;
    const int wave = tx >> 6, lane = tx & 63;
    const int quad = lane >> 4, lr = lane & 15;

    const int l = blockIdx.x;
    const int xcd = l & 7, s = l >> 3;
    const int mi = xcd * 8 + (s & 7), ci = s >> 3;
    const int m0 = mi * 64, c0 = ci * 64;
    const int wm = wave >> 1, wn = wave & 1;   // 32x32 quadrant per wave

    // A staging: thread t owns LDS slot t*16B = (row=t>>2, pos=t&3); fetches
    // logical k-chunk lc = (pos - (row>>1)) & 3 of its row.
    const int srow   = tx >> 2;
    const int schunk = ((tx & 3) - (srow >> 1)) & 3;
    const __bf16* gA = A + (size_t)(m0 + srow) * 4096 + schunk * 8;
    __bf16* lA0_ = &As[0][0][tx * 8];
    __bf16* lA1_ = &As[0][1][tx * 8];

    // reader swizzle: pos = (quad + (lr>>1))&3 (independent of i)
    const int pos = (quad + (lr >> 1)) & 3;
    const int arow0 = (wm * 32 + lr) * 32 + pos * 8;

    // B direct-global: lane (quad,lr) of wave(wn) holds
    // Bt[c0 + wn*32 + j*16 + lr][kt*64 + kh*32 + quad*8 .. +8]
    const __bf16* gB = Bt + (size_t)(c0 + wn * 32 + lr) * 4096 + quad * 8;

    f32x4 acc[2][2] = {};
    bf16x8 bfr[2][2][2];                 // [parity][kh][j]

    // prologue: stage A tile 0 into buf 0; load B frags for kt=0
    async_copy16(gA,      lA0_);
    async_copy16(gA + 32, lA1_);
    bfr[0][0][0] = *(const bf16x8*)(gB);
    bfr[0][0][1] = *(const bf16x8*)(gB + 16 * 4096);
    bfr[0][1][0] = *(const bf16x8*)(gB + 32);
    bfr[0][1][1] = *(const bf16x8*)(gB + 16 * 4096 + 32);

    auto phase = [&](int kt, int par) {
        __syncthreads();                 // drains vmcnt -> A buf + B regs ready
        if (kt + 1 < 64) {
            const int ko = (kt + 1) * 64;
            const int bo = (par ^ 1) * 4096;
            async_copy16(gA + ko,      lA0_ + bo);
            async_copy16(gA + ko + 32, lA1_ + bo);
            bfr[par ^ 1][0][0] = *(const bf16x8*)(gB + ko);
            bfr[par ^ 1][0][1] = *(const bf16x8*)(gB + ko + 16 * 4096);
            bfr[par ^ 1][1][0] = *(const bf16x8*)(gB + ko + 32);
            bfr[par ^ 1][1][1] = *(const bf16x8*)(gB + ko + 16 * 4096 + 32);
        }
#pragma unroll
        for (int kh = 0; kh < 2; ++kh) {
            bf16x8 a0 = *(const bf16x8*)(&As[par][kh][arow0]);
            bf16x8 a1 = *(const bf16x8*)(&As[par][kh][arow0 + 512]);
            acc[0][0] = __builtin_amdgcn_mfma_f32_16x16x32_bf16(a0, bfr[par][kh][0], acc[0][0], 0, 0, 0);
            acc[0][1] = __builtin_amdgcn_mfma_f32_16x16x32_bf16(a0, bfr[par][kh][1], acc[0][1], 0, 0, 0);
            acc[1][0] = __builtin_amdgcn_mfma_f32_16x16x32_bf16(a1, bfr[par][kh][0], acc[1][0], 0, 0, 0);
            acc[1][1] = __builtin_amdgcn_mfma_f32_16x16x32_bf16(a1, bfr[par][kh][1], acc[1][1], 0, 0, 0);
        }
    };
    for (int ktp = 0; ktp < 32; ++ktp) {
        phase(2 * ktp,     0);
        phase(2 * ktp + 1, 1);
    }

    // ---- fused epilogue (Ct separate from As: no WAR hazard on K-loop LDS) ----
#pragma unroll
    for (int i = 0; i < 2; ++i)
#pragma unroll
        for (int j = 0; j < 2; ++j)
#pragma unroll
            for (int r = 0; r < 4; ++r)
                Ct[(wm * 32 + i * 16 + quad * 4 + r) * 65 + wn * 32 + j * 16 + lr] = acc[i][j][r];
    __syncthreads();

    const int m_l = tx & 63, bq = tx >> 6;   // 64 cols = 16 whole batches (FI=4)
    if (MODE == 0) {
        const float b0f = ba[0], b1f = ba[1], b2f = ba[2], b3f = ba[3];
#pragma unroll
        for (int q = 0; q < 4; ++q) {
            const int bl = bq * 4 + q;
            const float* row = &Ct[m_l * 65 + bl * 4];
            __bf16* o = Hout + (size_t)(c0 + bl * 4) * N_NODE + m0 + m_l;
            o[0 * N_NODE] = (__bf16)fmaxf(row[0] + b0f, 0.f);
            o[1 * N_NODE] = (__bf16)fmaxf(row[1] + b1f, 0.f);
            o[2 * N_NODE] = (__bf16)fmaxf(row[2] + b2f, 0.f);
            o[3 * N_NODE] = (__bf16)fmaxf(row[3] + b3f, 0.f);
        }
    } else if (MODE == 1) {
        float W2l[16], W3l[12], bl2[4];
#pragma unroll
        for (int i = 0; i < 16; ++i) W2l[i] = Wa[i];
#pragma unroll
        for (int i = 0; i < 12; ++i) W3l[i] = Wb[i];
#pragma unroll
        for (int i = 0; i < 4; ++i) bl2[i] = ba[i];
#pragma unroll
        for (int q = 0; q < 4; ++q) {
            const int bl = bq * 4 + q;
            const float* row = &Ct[m_l * 65 + bl * 4];
            float tmp[4];
#pragma unroll
            for (int fo = 0; fo < 4; ++fo)
                tmp[fo] = fmaxf(row[0] * W2l[fo] + row[1] * W2l[4 + fo] +
                                row[2] * W2l[8 + fo] + row[3] * W2l[12 + fo] + bl2[fo], 0.f);
            __bf16* o = Hout + (size_t)(c0 + bl * 4) * N_NODE + m0 + m_l;
#pragma unroll
            for (int f3 = 0; f3 < 3; ++f3)
                o[f3 * N_NODE] = (__bf16)(tmp[0] * W3l[f3] + tmp[1] * W3l[3 + f3] +
                                          tmp[2] * W3l[6 + f3] + tmp[3] * W3l[9 + f3]);
            o[3 * N_NODE] = (__bf16)0.f;     // pad column for stage-3 gemm
        }
    } else {
        const float b0f = ba[0], b1f = ba[1], b2f = ba[2];
#pragma unroll
        for (int q = 0; q < 4; ++q) {
            const int bl = bq * 4 + q;
            const int b = ci * 16 + bl;
            const float* row = &Ct[m_l * 65 + bl * 4];
            float* o = H3out + (size_t)(b * 3) * N_NODE + m0 + m_l;
            o[0 * N_NODE] = fmaxf(row[0] + b0f, 0.f);
            o[1 * N_NODE] = fmaxf(row[1] + b1f, 0.f);
            o[2 * N_NODE] = fmaxf(row[2] + b2f, 0.f);
        }
    }
}

// fc1 split-K partial sums: grid (64 n-chunks, 8 b-groups of 16).
__global__ __launch_bounds__(256) void fc1p_k(const float* __restrict__ H3,
                                              const float* __restrict__ Wfc,
                                              float* __restrict__ hid_acc) {
    __shared__ float hs[16 * 192];       // [b][f][n]
    __shared__ float red[4][16][64];
    const int tx = threadIdx.x;
    const int wv = tx >> 6, lane = tx & 63;
    const int n0 = blockIdx.x * 64;
    const int b0 = blockIdx.y * 16;

    for (int idx = tx; idx < 3072; idx += 256) {
        const int n = idx & 63, f = (idx >> 6) % 3, b = idx / 192;
        hs[idx] = H3[((size_t)((b0 + b) * 3 + f)) * N_NODE + n0 + n];
    }
    __syncthreads();

    float acc[16];
#pragma unroll
    for (int b = 0; b < 16; ++b) acc[b] = 0.f;
    if (lane < 54) {
        const int nb = wv * 16;
        for (int n = 0; n < 16; ++n) {
#pragma unroll
            for (int f = 0; f < 3; ++f) {
                const float w = Wfc[((size_t)(n0 + nb + n) * 3 + f) * 54 + lane];
#pragma unroll
                for (int b = 0; b < 16; ++b)
                    acc[b] += hs[b * 192 + f * 64 + nb + n] * w;
            }
        }
    }
#pragma unroll
    for (int b = 0; b < 16; ++b) red[wv][b][lane] = acc[b];
    __syncthreads();
    if (wv == 0 && lane < 54) {
        for (int b = 0; b < 16; ++b) {
            const float s = red[0][b][lane] + red[1][b][lane] +
                            red[2][b][lane] + red[3][b][lane];
            atomicAdd(&hid_acc[(b0 + b) * 54 + lane], s);
        }
    }
}

// out[b][a] = sum_j relu(hid_acc[b][j]+bfc[j]) * Wout[j][a] + bout[a]
__global__ __launch_bounds__(256) void fc2_k(const float* __restrict__ hid_acc,
                                             const float* __restrict__ bfc,
                                             const float* __restrict__ Wout,
                                             const float* __restrict__ bout,
                                             float* __restrict__ out) {
    const int tx = threadIdx.x;
    const int a  = blockIdx.x * 256 + tx;
    const int b0 = blockIdx.y * 4;
    __shared__ float hs[4 * 54];
    if (tx < 216) {
        const int j = tx % 54;
        hs[tx] = fmaxf(hid_acc[b0 * 54 + tx] + bfc[j], 0.f);
    }
    __syncthreads();
    float a0 = 0.f, a1 = 0.f, a2 = 0.f, a3 = 0.f;
    for (int j = 0; j < 54; ++j) {
        float w = Wout[(size_t)j * N_NODE + a];
        a0 += hs[0 * 54 + j] * w;
        a1 += hs[1 * 54 + j] * w;
        a2 += hs[2 * 54 + j] * w;
        a3 += hs[3 * 54 + j] * w;
    }
    float bo = bout[a];
    out[(size_t)(b0 + 0) * N_NODE + a] = a0 + bo;
    out[(size_t)(b0 + 1) * N_NODE + a] = a1 + bo;
    out[(size_t)(b0 + 2) * N_NODE + a] = a2 + bo;
    out[(size_t)(b0 + 3) * N_NODE + a] = a3 + bo;
}

extern "C" void kernel_launch(void* const* d_in, const int* in_sizes, int n_in,
                              void* d_out, int out_size, void* d_ws, size_t ws_size,
                              hipStream_t stream) {
    const float* X    = (const float*)d_in[0];
    const float* adj  = (const float*)d_in[1];
    const float* W1   = (const float*)d_in[2];
    const float* b1   = (const float*)d_in[3];
    const float* W2   = (const float*)d_in[4];
    const float* b2   = (const float*)d_in[5];
    const float* W3   = (const float*)d_in[6];
    const float* b3   = (const float*)d_in[7];
    const float* Wfc  = (const float*)d_in[8];
    const float* bfc  = (const float*)d_in[9];
    const float* Wout = (const float*)d_in[10];
    const float* bout = (const float*)d_in[11];
    float* out = (float*)d_out;

    // ws: adjB 32MB | G0 bf16 [512][4096] 4MB | H1 bf16 4MB | H2g bf16 4MB
    //   | H3 fp32 [384][4096] 6MB | hid [128][54]
    char* w = (char*)d_ws;
    __bf16* adjB = (__bf16*)w;
    __bf16* G0   = (__bf16*)(w + 33554432);
    __bf16* H1   = (__bf16*)(w + 33554432 + 4194304);
    __bf16* H2g  = (__bf16*)(w + 33554432 + 2 * 4194304);
    float*  H3   = (float*)(w + 33554432 + 3 * 4194304);
    float*  hid  = (float*)(w + 33554432 + 3 * 4194304 + 6291456);

    prep_k<<<10267, 256, 0, stream>>>(adj, adjB, X, W1, G0, hid);

    // stage 1: H1 = relu(adj @ G0^T + b1)          (W1 pre-applied in prep)
    gcn_k<0><<<512, 256, 0, stream>>>(adjB, G0, nullptr, b1, nullptr, H1, nullptr);
    // stage 2: H2g = (relu(adj @ H1^T @ W2 + b2)) @ W3, padded f=4
    gcn_k<1><<<512, 256, 0, stream>>>(adjB, H1, W2, b2, W3, H2g, nullptr);
    // stage 3: H3 = relu(adj @ H2g^T + b3), f<3, fp32
    gcn_k<2><<<512, 256, 0, stream>>>(adjB, H2g, nullptr, b3, nullptr, nullptr, H3);

    // FC head
    fc1p_k<<<dim3(64, 8), 256, 0, stream>>>(H3, Wfc, hid);
    fc2_k<<<dim3(16, 32), 256, 0, stream>>>(hid, bfc, Wout, bout, out);
}

// Round 9
// 226.544 us; speedup vs baseline: 1.5083x; 1.5083x over previous
//
#include <hip/hip_runtime.h>

// ---------------------------------------------------------------------------
// sxsGCN: h=[B=128,N=4096,3]; 3x { relu((adj@h)@W+b) }; then FC 12288->54->4096
// bf16 MFMA GEMMs adj[4096x4096] @ H[4096 x 512], H transposed [b*4+f][m].
// R1: fc1 split-K + atomics: 275us -> ~15us.
// R2: gemm double-buffered BK=64: 62 -> 47us.
// R3: XOR-swizzled LDS (conflicts 4.2e6 -> 0): LDS/feed-bound, not conflicts.
// R4: 128x128+split-K atomics: 1 block/CU -> 53us FAIL.
// R5: deeper split-K: atomic epilogues: 61.5us FAIL.
// R6: W1 folded into prep, W2*W3 chained, epilogue fused into gemm: 234us.
//     Harness 0xAA ws-fill (~41us @ 83% HBM) sits inside the timed window.
// R7: B operand direct global->VGPR: 69us FAIL. Frag layout = 16 rows x 8KB
//     stride per load -> 16 cache lines/instr chokes VMEM issue. Lesson:
//     MFMA operands from global need coalesced lanes; frag layouts aren't.
// R8: LDS-pipe bound confirmed (48KB/block-iter ~ 750 clk/CU ~ observed).
//     K-sliced waves: BK=128 macro-tile, each wave computes the full 64x64
//     over its private k-slice of 32 (4x4 acc) -> every frag read ONCE:
//     LDS 96->64KB per BK=128, barriers halved. Cross-wave reduce + wave-0
//     transpose at end (one-time). LDS exactly 64KB -> 2 blocks/CU.
// ---------------------------------------------------------------------------

typedef __bf16 bf16x8 __attribute__((ext_vector_type(8)));
typedef float  f32x4  __attribute__((ext_vector_type(4)));

#define N_NODE 4096
#define BATCH  128

__device__ __forceinline__ void async_copy16(const void* gsrc, void* ldst) {
    __builtin_amdgcn_global_load_lds(
        (const __attribute__((address_space(1))) void*)gsrc,
        (__attribute__((address_space(3))) void*)ldst,
        16, 0, 0);
}

// prep: [0,8192) cast adj->bf16 | [8192,10240) G0[b*4+f][m] = (X@W1)^T bf16
//       | [10240,10267) zero hid
__global__ __launch_bounds__(256) void prep_k(const float* __restrict__ adj,
                                              __bf16* __restrict__ adjB,
                                              const float* __restrict__ X,
                                              const float* __restrict__ W1,
                                              __bf16* __restrict__ G0,
                                              float* __restrict__ hid_acc) {
    const int blk = blockIdx.x, tx = threadIdx.x;
    if (blk < 8192) {
        const size_t i = (size_t)blk * 256 + tx;       // group of 8
        const float4* a4 = (const float4*)adj;
        float4 u = a4[i * 2];
        float4 v = a4[i * 2 + 1];
        bf16x8 o = { (__bf16)u.x, (__bf16)u.y, (__bf16)u.z, (__bf16)u.w,
                     (__bf16)v.x, (__bf16)v.y, (__bf16)v.z, (__bf16)v.w };
        *(bf16x8*)(adjB + i * 8) = o;
    } else if (blk < 10240) {
        const int base = (blk - 8192) * 1024;          // c uniform per block
        const int c = base >> 12, b = c >> 2, f = c & 3;
        const float w0 = W1[0 * 4 + f], w1 = W1[1 * 4 + f], w2 = W1[2 * 4 + f];
        const float* Xb = X + (size_t)b * 12288;
#pragma unroll
        for (int k = 0; k < 4; ++k) {
            const int idx = base + k * 256 + tx;       // < 512*4096
            const int m = idx & 4095;
            const float v = Xb[m * 3 + 0] * w0 + Xb[m * 3 + 1] * w1 + Xb[m * 3 + 2] * w2;
            G0[idx] = (__bf16)v;
        }
    } else {
        const int i = (blk - 10240) * 256 + tx;
        if (i < BATCH * 54) hid_acc[i] = 0.f;
    }
}

// Fused GEMM + epilogue, k-sliced waves.
// C[m][c] = sum_k adjB[m][k] * Ht[c][k]; block tile 64x64, BK=128 macro-tile.
// LDS: A[64][128] + B[64][128] bf16, double-buffered (64KB). Chunk (row r,
// 16B pos p) stores logical k-chunk lk = (p - r) & 15 (XOR-ish swizzle ->
// frag reads conflict-free). Wave w computes the FULL 64x64 over k-slice
// [w*32, w*32+32) of each macro-tile: 8 ds_read_b128 + 16 MFMA per iter,
// every fragment read once. End: waves 1-3 write partials (lane-linear,
// swizzled), wave 0 reduces + transposes into Ct[64][65] @ +32KB, all
// threads run the MODE epilogue:
//   MODE 0: h1 = relu(C + b1[f])                       -> Hout bf16
//   MODE 1: g2 = relu(C@W2 + b2) @ W3, f=3 col zeroed  -> Hout bf16
//   MODE 2: h3 = relu(C + b3[f]), f<3                  -> H3out fp32
// XCD swizzle: l&7 = xcd; mi = xcd*8 + (s&7), ci = s>>3.
template <int MODE>
__global__ __launch_bounds__(256) void gcn_k(const __bf16* __restrict__ A,
                                             const __bf16* __restrict__ Bt,
                                             const float* __restrict__ Wa,
                                             const float* __restrict__ ba,
                                             const float* __restrict__ Wb,
                                             __bf16* __restrict__ Hout,
                                             float* __restrict__ H3out) {
    __shared__ __align__(16) unsigned char smem[65536];
    // buf b: A at b*32768, B at b*32768+16384 (16KB each)
    // epilogue: partial slot s (waves 1..3) at s*16384; Ct[64][65] at +32768
    const int tx   = threadIdx.x;
    const int wave = tx >> 6, lane = tx & 63;
    const int quad = lane >> 4, lr = lane & 15;

    const int l = blockIdx.x;
    const int xcd = l & 7, s = l >> 3;
    const int mi = xcd * 8 + (s & 7), ci = s >> 3;
    const int m0 = mi * 64, c0 = ci * 64;

    // staging: 1024 chunks of 16B per matrix per buffer; thread t, issue q
    // owns chunk c = q*256 + t -> row r = c>>4, pos p = c&15, fetches logical
    // k-chunk lk = (p - r) & 15. LDS dst = base + c*16 (wave-uniform + lane*16).
    const __bf16* gA[4];
    const __bf16* gB[4];
#pragma unroll
    for (int q = 0; q < 4; ++q) {
        const int c = q * 256 + tx;
        const int r = c >> 4, p = c & 15;
        const int lk = (p - (r & 15)) & 15;
        gA[q] = A  + (size_t)(m0 + r) * 4096 + lk * 8;
        gB[q] = Bt + (size_t)(c0 + r) * 4096 + lk * 8;
    }

    // frag read offsets (elements): row (g*16+lr), logical k-chunk wave*4+quad
    // stored at pos (wave*4+quad+lr)&15.
    const int posw = ((wave * 4 + quad + lr) & 15) * 8;
    int foff[4];
#pragma unroll
    for (int g = 0; g < 4; ++g) foff[g] = (g * 16 + lr) * 128 + posw;

    f32x4 acc[4][4] = {};

    // prologue: stage macro-tile 0 into buf 0
#pragma unroll
    for (int q = 0; q < 4; ++q) {
        async_copy16(gA[q], smem + q * 4096 + tx * 16);
        async_copy16(gB[q], smem + 16384 + q * 4096 + tx * 16);
    }

    int buf = 0;
    for (int kt = 0; kt < 32; ++kt) {
        __syncthreads();                 // drains vmcnt -> buf ready
        if (kt + 1 < 32) {
            const int k0 = (kt + 1) * 128;
            const int bo = (buf ^ 1) * 32768;
#pragma unroll
            for (int q = 0; q < 4; ++q) {
                async_copy16(gA[q] + k0, smem + bo + q * 4096 + tx * 16);
                async_copy16(gB[q] + k0, smem + bo + 16384 + q * 4096 + tx * 16);
            }
        }
        const __bf16* Ab = (const __bf16*)(smem + buf * 32768);
        const __bf16* Bb = (const __bf16*)(smem + buf * 32768 + 16384);
        bf16x8 af[4], bv[4];
#pragma unroll
        for (int i = 0; i < 4; ++i) af[i] = *(const bf16x8*)(Ab + foff[i]);
#pragma unroll
        for (int j = 0; j < 4; ++j) bv[j] = *(const bf16x8*)(Bb + foff[j]);
#pragma unroll
        for (int i = 0; i < 4; ++i)
#pragma unroll
            for (int j = 0; j < 4; ++j)
                acc[i][j] = __builtin_amdgcn_mfma_f32_16x16x32_bf16(af[i], bv[j], acc[i][j], 0, 0, 0);
        buf ^= 1;
    }

    // ---- cross-wave k-reduce (partials in C-layout-agnostic lane-linear form) ----
    __syncthreads();                     // all LDS reads of K-loop done
    float* part = (float*)smem;
    if (wave != 0) {
        float* slot = part + (wave - 1) * 4096;
#pragma unroll
        for (int t = 0; t < 16; ++t)
            *(f32x4*)(slot + lane * 64 + ((t + lane) & 15) * 4) = acc[t >> 2][t & 3];
    }
    __syncthreads();
    float* Ct = (float*)(smem + 32768);  // [64][65]
    if (wave == 0) {
#pragma unroll
        for (int t = 0; t < 16; ++t) {
            const int o = lane * 64 + ((t + lane) & 15) * 4;
            f32x4 p0 = *(const f32x4*)(part + o);
            f32x4 p1 = *(const f32x4*)(part + 4096 + o);
            f32x4 p2 = *(const f32x4*)(part + 8192 + o);
            acc[t >> 2][t & 3] += p0 + p1 + p2;
        }
        // transpose-scatter into Ct (C/D: col=lane&15, row=quad*4+reg)
#pragma unroll
        for (int i = 0; i < 4; ++i)
#pragma unroll
            for (int j = 0; j < 4; ++j)
#pragma unroll
                for (int r = 0; r < 4; ++r)
                    Ct[(i * 16 + quad * 4 + r) * 65 + j * 16 + lr] = acc[i][j][r];
    }
    __syncthreads();

    const int m_l = tx & 63, bq = tx >> 6;   // 64 cols = 16 whole batches (FI=4)
    if (MODE == 0) {
        const float b0f = ba[0], b1f = ba[1], b2f = ba[2], b3f = ba[3];
#pragma unroll
        for (int q = 0; q < 4; ++q) {
            const int bl = bq * 4 + q;
            const float* row = &Ct[m_l * 65 + bl * 4];
            __bf16* o = Hout + (size_t)(c0 + bl * 4) * N_NODE + m0 + m_l;
            o[0 * N_NODE] = (__bf16)fmaxf(row[0] + b0f, 0.f);
            o[1 * N_NODE] = (__bf16)fmaxf(row[1] + b1f, 0.f);
            o[2 * N_NODE] = (__bf16)fmaxf(row[2] + b2f, 0.f);
            o[3 * N_NODE] = (__bf16)fmaxf(row[3] + b3f, 0.f);
        }
    } else if (MODE == 1) {
        float W2l[16], W3l[12], bl2[4];
#pragma unroll
        for (int i = 0; i < 16; ++i) W2l[i] = Wa[i];
#pragma unroll
        for (int i = 0; i < 12; ++i) W3l[i] = Wb[i];
#pragma unroll
        for (int i = 0; i < 4; ++i) bl2[i] = ba[i];
#pragma unroll
        for (int q = 0; q < 4; ++q) {
            const int bl = bq * 4 + q;
            const float* row = &Ct[m_l * 65 + bl * 4];
            float tmp[4];
#pragma unroll
            for (int fo = 0; fo < 4; ++fo)
                tmp[fo] = fmaxf(row[0] * W2l[fo] + row[1] * W2l[4 + fo] +
                                row[2] * W2l[8 + fo] + row[3] * W2l[12 + fo] + bl2[fo], 0.f);
            __bf16* o = Hout + (size_t)(c0 + bl * 4) * N_NODE + m0 + m_l;
#pragma unroll
            for (int f3 = 0; f3 < 3; ++f3)
                o[f3 * N_NODE] = (__bf16)(tmp[0] * W3l[f3] + tmp[1] * W3l[3 + f3] +
                                          tmp[2] * W3l[6 + f3] + tmp[3] * W3l[9 + f3]);
            o[3 * N_NODE] = (__bf16)0.f;     // pad column for stage-3 gemm
        }
    } else {
        const float b0f = ba[0], b1f = ba[1], b2f = ba[2];
#pragma unroll
        for (int q = 0; q < 4; ++q) {
            const int bl = bq * 4 + q;
            const int b = ci * 16 + bl;
            const float* row = &Ct[m_l * 65 + bl * 4];
            float* o = H3out + (size_t)(b * 3) * N_NODE + m0 + m_l;
            o[0 * N_NODE] = fmaxf(row[0] + b0f, 0.f);
            o[1 * N_NODE] = fmaxf(row[1] + b1f, 0.f);
            o[2 * N_NODE] = fmaxf(row[2] + b2f, 0.f);
        }
    }
}

// fc1 split-K partial sums: grid (64 n-chunks, 8 b-groups of 16).
__global__ __launch_bounds__(256) void fc1p_k(const float* __restrict__ H3,
                                              const float* __restrict__ Wfc,
                                              float* __restrict__ hid_acc) {
    __shared__ float hs[16 * 192];       // [b][f][n]
    __shared__ float red[4][16][64];
    const int tx = threadIdx.x;
    const int wv = tx >> 6, lane = tx & 63;
    const int n0 = blockIdx.x * 64;
    const int b0 = blockIdx.y * 16;

    for (int idx = tx; idx < 3072; idx += 256) {
        const int n = idx & 63, f = (idx >> 6) % 3, b = idx / 192;
        hs[idx] = H3[((size_t)((b0 + b) * 3 + f)) * N_NODE + n0 + n];
    }
    __syncthreads();

    float acc[16];
#pragma unroll
    for (int b = 0; b < 16; ++b) acc[b] = 0.f;
    if (lane < 54) {
        const int nb = wv * 16;
        for (int n = 0; n < 16; ++n) {
#pragma unroll
            for (int f = 0; f < 3; ++f) {
                const float w = Wfc[((size_t)(n0 + nb + n) * 3 + f) * 54 + lane];
#pragma unroll
                for (int b = 0; b < 16; ++b)
                    acc[b] += hs[b * 192 + f * 64 + nb + n] * w;
            }
        }
    }
#pragma unroll
    for (int b = 0; b < 16; ++b) red[wv][b][lane] = acc[b];
    __syncthreads();
    if (wv == 0 && lane < 54) {
        for (int b = 0; b < 16; ++b) {
            const float s = red[0][b][lane] + red[1][b][lane] +
                            red[2][b][lane] + red[3][b][lane];
            atomicAdd(&hid_acc[(b0 + b) * 54 + lane], s);
        }
    }
}

// out[b][a] = sum_j relu(hid_acc[b][j]+bfc[j]) * Wout[j][a] + bout[a]
__global__ __launch_bounds__(256) void fc2_k(const float* __restrict__ hid_acc,
                                             const float* __restrict__ bfc,
                                             const float* __restrict__ Wout,
                                             const float* __restrict__ bout,
                                             float* __restrict__ out) {
    const int tx = threadIdx.x;
    const int a  = blockIdx.x * 256 + tx;
    const int b0 = blockIdx.y * 4;
    __shared__ float hs[4 * 54];
    if (tx < 216) {
        const int j = tx % 54;
        hs[tx] = fmaxf(hid_acc[b0 * 54 + tx] + bfc[j], 0.f);
    }
    __syncthreads();
    float a0 = 0.f, a1 = 0.f, a2 = 0.f, a3 = 0.f;
    for (int j = 0; j < 54; ++j) {
        float w = Wout[(size_t)j * N_NODE + a];
        a0 += hs[0 * 54 + j] * w;
        a1 += hs[1 * 54 + j] * w;
        a2 += hs[2 * 54 + j] * w;
        a3 += hs[3 * 54 + j] * w;
    }
    float bo = bout[a];
    out[(size_t)(b0 + 0) * N_NODE + a] = a0 + bo;
    out[(size_t)(b0 + 1) * N_NODE + a] = a1 + bo;
    out[(size_t)(b0 + 2) * N_NODE + a] = a2 + bo;
    out[(size_t)(b0 + 3) * N_NODE + a] = a3 + bo;
}

extern "C" void kernel_launch(void* const* d_in, const int* in_sizes, int n_in,
                              void* d_out, int out_size, void* d_ws, size_t ws_size,
                              hipStream_t stream) {
    const float* X    = (const float*)d_in[0];
    const float* adj  = (const float*)d_in[1];
    const float* W1   = (const float*)d_in[2];
    const float* b1   = (const float*)d_in[3];
    const float* W2   = (const float*)d_in[4];
    const float* b2   = (const float*)d_in[5];
    const float* W3   = (const float*)d_in[6];
    const float* b3   = (const float*)d_in[7];
    const float* Wfc  = (const float*)d_in[8];
    const float* bfc  = (const float*)d_in[9];
    const float* Wout = (const float*)d_in[10];
    const float* bout = (const float*)d_in[11];
    float* out = (float*)d_out;

    // ws: adjB 32MB | G0 bf16 [512][4096] 4MB | H1 bf16 4MB | H2g bf16 4MB
    //   | H3 fp32 [384][4096] 6MB | hid [128][54]
    char* w = (char*)d_ws;
    __bf16* adjB = (__bf16*)w;
    __bf16* G0   = (__bf16*)(w + 33554432);
    __bf16* H1   = (__bf16*)(w + 33554432 + 4194304);
    __bf16* H2g  = (__bf16*)(w + 33554432 + 2 * 4194304);
    float*  H3   = (float*)(w + 33554432 + 3 * 4194304);
    float*  hid  = (float*)(w + 33554432 + 3 * 4194304 + 6291456);

    prep_k<<<10267, 256, 0, stream>>>(adj, adjB, X, W1, G0, hid);

    // stage 1: H1 = relu(adj @ G0^T + b1)          (W1 pre-applied in prep)
    gcn_k<0><<<512, 256, 0, stream>>>(adjB, G0, nullptr, b1, nullptr, H1, nullptr);
    // stage 2: H2g = (relu(adj @ H1^T @ W2 + b2)) @ W3, padded f=4
    gcn_k<1><<<512, 256, 0, stream>>>(adjB, H1, W2, b2, W3, H2g, nullptr);
    // stage 3: H3 = relu(adj @ H2g^T + b3), f<3, fp32
    gcn_k<2><<<512, 256, 0, stream>>>(adjB, H2g, nullptr, b3, nullptr, nullptr, H3);

    // FC head
    fc1p_k<<<dim3(64, 8), 256, 0, stream>>>(H3, Wfc, hid);
    fc2_k<<<dim3(16, 32), 256, 0, stream>>>(hid, bfc, Wout, bout, out);
}